// Round 9
// baseline (216.045 us; speedup 1.0000x reference)
//
#include <hip/hip_runtime.h>
#include <math.h>

// GCN 2-layer: out = Anorm( relu( Anorm(X W1) + b1 ) W2 ) + b2
// R9: XCD-privatized histogram — counts replicated x8 (group = blockIdx&7,
//     aligned with round-robin block->XCD dispatch). Atomics stay XCD-local,
//     killing cross-XCD line ping-pong that R8 showed is the count_rank
//     bottleneck (4x ILP gained ~nothing -> serialization, not slots).
//     scan1 computes per-(group,node) scatter bases gbase; scatter uses
//     gbase[g][dst]+rank (same gather count as before). Rest unchanged.

typedef __bf16 bf16x8 __attribute__((ext_vector_type(8)));
typedef float f32x4 __attribute__((ext_vector_type(4)));

constexpr int NG = 8;  // histogram replicas (≈ XCDs)

union ABu {
  unsigned short u16[8];
  uint4 u4;
  bf16x8 v;
};

__device__ inline unsigned short f2bf(float f) {  // RNE
  unsigned u = __float_as_uint(f);
  return (unsigned short)((u + 0x7fffu + ((u >> 16) & 1u)) >> 16);
}

__device__ inline void unpack8(uint4 v, float* f) {
  f[0] = __uint_as_float(v.x << 16);
  f[1] = __uint_as_float(v.x & 0xffff0000u);
  f[2] = __uint_as_float(v.y << 16);
  f[3] = __uint_as_float(v.y & 0xffff0000u);
  f[4] = __uint_as_float(v.z << 16);
  f[5] = __uint_as_float(v.z & 0xffff0000u);
  f[6] = __uint_as_float(v.w << 16);
  f[7] = __uint_as_float(v.w & 0xffff0000u);
}

__device__ inline uint4 pack8(const float* a) {
  uint4 o;
  o.x = (unsigned)f2bf(a[0]) | ((unsigned)f2bf(a[1]) << 16);
  o.y = (unsigned)f2bf(a[2]) | ((unsigned)f2bf(a[3]) << 16);
  o.z = (unsigned)f2bf(a[4]) | ((unsigned)f2bf(a[5]) << 16);
  o.w = (unsigned)f2bf(a[6]) | ((unsigned)f2bf(a[7]) << 16);
  return o;
}

constexpr int SCAN_CHUNK = 1024;

// ---------------- 1: convW ∪ zero counts (8 replicas) ----------------
__global__ __launch_bounds__(256) void k_pre(const float* __restrict__ W1,
                                             const float* __restrict__ W2,
                                             unsigned short* __restrict__ Wb1,
                                             unsigned short* __restrict__ Wb2,
                                             int* __restrict__ counts, int n8) {
  constexpr int CONV_BLOCKS = (128 * 128 + 128 * 64) / 256;  // 96
  if (blockIdx.x < CONV_BLOCKS) {
    int idx = blockIdx.x * 256 + threadIdx.x;
    if (idx < 128 * 128) {
      int k = idx >> 7, c = idx & 127;
      Wb1[(((k >> 3) << 7) + c) * 8 + (k & 7)] = f2bf(W1[idx]);
    } else {
      int j = idx - 128 * 128;
      int k = j >> 6, c = j & 63;
      Wb2[(((k >> 3) << 6) + c) * 8 + (k & 7)] = f2bf(W2[j]);
    }
    return;
  }
  int i = (blockIdx.x - CONV_BLOCKS) * 256 + threadIdx.x;
  if (i < n8) counts[i] = 0;
}

// ---------------- 2: count + rank into group-private tables ----------------
// group g = blockIdx & 7 (heuristically XCD-aligned; any partition is correct)
__global__ __launch_bounds__(256) void k_count_rank(const int* __restrict__ dst,
                                                    int* __restrict__ counts,
                                                    int* __restrict__ rank,
                                                    int E, int N) {
  int* cnt = counts + (size_t)(blockIdx.x & (NG - 1)) * N;
  int base = (blockIdx.x * 256 + threadIdx.x) * 4;
  if (base + 3 < E) {
    int4 d = *(const int4*)(dst + base);
    int4 r;
    r.x = atomicAdd(&cnt[d.x], 1);
    r.y = atomicAdd(&cnt[d.y], 1);
    r.z = atomicAdd(&cnt[d.z], 1);
    r.w = atomicAdd(&cnt[d.w], 1);
    *(int4*)(rank + base) = r;
  } else {
    for (int e = base; e < E; ++e) rank[e] = atomicAdd(&cnt[dst[e]], 1);
  }
}

// ---------------- 3: per-chunk scan over totals + group bases + dinv -------
__global__ __launch_bounds__(256) void k_scan1(const int* __restrict__ counts,
                                               int* __restrict__ offsets,
                                               int* __restrict__ gbase,
                                               int* __restrict__ aux,
                                               float* __restrict__ dinv, int n) {
  __shared__ int tsum[256];
  int tid = threadIdx.x;
  int base = blockIdx.x * SCAN_CHUNK + tid * 4;

  int tot[4];
  int pre[4][NG];  // per-node exclusive prefix over groups
#pragma unroll
  for (int j = 0; j < 4; ++j) {
    int i = base + j;
    int t = 0;
    if (i < n) {
#pragma unroll
      for (int g = 0; g < NG; ++g) {
        pre[j][g] = t;
        t += counts[(size_t)g * n + i];
      }
    } else {
#pragma unroll
      for (int g = 0; g < NG; ++g) pre[j][g] = 0;
    }
    tot[j] = t;
  }
  int s = tot[0] + tot[1] + tot[2] + tot[3];
  tsum[tid] = s;
  __syncthreads();
  for (int off = 1; off < 256; off <<= 1) {
    int t = (tid >= off) ? tsum[tid - off] : 0;
    __syncthreads();
    tsum[tid] += t;
    __syncthreads();
  }
  int excl = tsum[tid] - s;

  int run = excl;
#pragma unroll
  for (int j = 0; j < 4; ++j) {
    int i = base + j;
    if (i < n) {
      offsets[i] = run;
      dinv[i] = rsqrtf((float)(tot[j] + 1));
#pragma unroll
      for (int g = 0; g < NG; ++g) gbase[(size_t)g * n + i] = run + pre[j][g];
      run += tot[j];
    }
  }
  if (tid == 255) aux[blockIdx.x] = tsum[255];
}

// ---------------- 4: aux-scan (redundant/block) + fixup (offsets + gbase) --
__global__ __launch_bounds__(256) void k_scan3(int* __restrict__ offsets,
                                               int* __restrict__ gbase,
                                               const int* __restrict__ aux,
                                               int n, int E, int G) {
  __shared__ int saux[256];
  int tid = threadIdx.x;
  int v = (tid < G) ? aux[tid] : 0;
  saux[tid] = v;
  __syncthreads();
  for (int off = 1; off < 256; off <<= 1) {
    int t = (tid >= off) ? saux[tid - off] : 0;
    __syncthreads();
    saux[tid] += t;
    __syncthreads();
  }
  int excl = saux[tid] - v;
  __syncthreads();
  saux[tid] = excl;
  __syncthreads();

  int i = blockIdx.x * 256 + tid;
  if (i < n) {
    int fix = saux[i >> 10];
    offsets[i] += fix;
#pragma unroll
    for (int g = 0; g < NG; ++g) gbase[(size_t)g * n + i] += fix;
  }
  if (i == 0) offsets[n] = E;
}

// ---------------- 5: atomic-free CSR scatter (same block->group map) -------
__global__ __launch_bounds__(256) void k_scatter(const int* __restrict__ src,
                                                 const int* __restrict__ dst,
                                                 const int* __restrict__ gbase,
                                                 const int* __restrict__ rank,
                                                 int* __restrict__ esrc, int E, int N) {
  const int* gb = gbase + (size_t)(blockIdx.x & (NG - 1)) * N;
  int base = (blockIdx.x * 256 + threadIdx.x) * 4;
  if (base + 3 < E) {
    int4 s = *(const int4*)(src + base);
    int4 d = *(const int4*)(dst + base);
    int4 r = *(const int4*)(rank + base);
    esrc[gb[d.x] + r.x] = s.x;
    esrc[gb[d.y] + r.y] = s.y;
    esrc[gb[d.z] + r.z] = s.z;
    esrc[gb[d.w] + r.w] = s.w;
  } else {
    for (int e = base; e < E; ++e) esrc[gb[dst[e]] + rank[e]] = src[e];
  }
}

// ---------------- 6: gemm1 — h1s[M,128](bf16) = dinv[row] * (X @ W1) -------
__global__ __launch_bounds__(256) void k_gemm1(const float* __restrict__ X,
                                               const unsigned short* __restrict__ Wb,
                                               const float* __restrict__ dinv,
                                               unsigned short* __restrict__ Cb, int M) {
  constexpr int K = 128, N = 128, NT = N / 16, KS = K / 32;
  const int tid = threadIdx.x;
  const int wave = tid >> 6;
  const int lane = tid & 63;
  const int q = lane >> 4;
  const int l15 = lane & 15;
  const int row0 = blockIdx.x * 64 + wave * 16;
  const int rowA = row0 + l15;

  f32x4 zero = {0.0f, 0.0f, 0.0f, 0.0f};
  f32x4 acc[NT];
#pragma unroll
  for (int t = 0; t < NT; ++t) acc[t] = zero;

#pragma unroll
  for (int kk = 0; kk < KS; ++kk) {
    ABu a;
    float4 f0 = make_float4(0.f, 0.f, 0.f, 0.f);
    float4 f1 = make_float4(0.f, 0.f, 0.f, 0.f);
    if (rowA < M) {
      const float4* ap = (const float4*)(X + (size_t)rowA * K + kk * 32 + q * 8);
      f0 = ap[0];
      f1 = ap[1];
    }
    a.u16[0] = f2bf(f0.x); a.u16[1] = f2bf(f0.y);
    a.u16[2] = f2bf(f0.z); a.u16[3] = f2bf(f0.w);
    a.u16[4] = f2bf(f1.x); a.u16[5] = f2bf(f1.y);
    a.u16[6] = f2bf(f1.z); a.u16[7] = f2bf(f1.w);
#pragma unroll
    for (int nt = 0; nt < NT; ++nt) {
      ABu b;
      b.u4 = *(const uint4*)(Wb + ((size_t)(kk * 4 + q) * N + nt * 16 + l15) * 8);
      acc[nt] = __builtin_amdgcn_mfma_f32_16x16x32_bf16(a.v, b.v, acc[nt], 0, 0, 0);
    }
  }

#pragma unroll
  for (int v = 0; v < 4; ++v) {
    int row = row0 + q * 4 + v;
    if (row < M) {
      float di = dinv[row];
#pragma unroll
      for (int nt = 0; nt < NT; ++nt)
        Cb[(size_t)row * N + nt * 16 + l15] = f2bf(acc[nt][v] * di);
    }
  }
}

// ---------------- 7: fused agg1 + GEMM2 ----------------
__global__ __launch_bounds__(256) void k_aggemm(const unsigned short* __restrict__ h1s,
                                                const float* __restrict__ dinv,
                                                const float* __restrict__ b1,
                                                const int* __restrict__ offsets,
                                                const int* __restrict__ esrc,
                                                const unsigned short* __restrict__ Wb2,
                                                unsigned short* __restrict__ h2s,
                                                int n) {
  constexpr int LDA = 136;  // 128 + 8 pad, rows 16B-aligned
  __shared__ unsigned short As[16 * LDA];
  __shared__ float sdinv[16];
  const int tid = threadIdx.x;

  {
    const int nl = tid >> 4;
    const int q = tid & 15;
    const int node = blockIdx.x * 16 + nl;
    float acc[8];
    if (node < n) {
      const uint4* h4 = (const uint4*)h1s;
      float di = dinv[node];
      if (q == 0) sdinv[nl] = di;
      unpack8(h4[(size_t)node * 16 + q], acc);  // self (pre-scaled)
      int e0 = offsets[node];
      int e1 = offsets[node + 1];
      for (int e = e0; e < e1; e += 8) {
        int idx[8];
#pragma unroll
        for (int i = 0; i < 8; ++i) {
          int ee = e + i < e1 ? e + i : e1 - 1;
          idx[i] = esrc[ee];
        }
        uint4 rr[8];
#pragma unroll
        for (int i = 0; i < 8; ++i) rr[i] = h4[(size_t)idx[i] * 16 + q];
#pragma unroll
        for (int i = 0; i < 8; ++i) {
          float w = (e + i < e1) ? 1.f : 0.f;
          float g[8];
          unpack8(rr[i], g);
#pragma unroll
          for (int j = 0; j < 8; ++j) acc[j] = fmaf(g[j], w, acc[j]);
        }
      }
      const float4* b14 = (const float4*)b1;
      float4 ba = b14[q * 2], bb = b14[q * 2 + 1];
      float bias[8] = {ba.x, ba.y, ba.z, ba.w, bb.x, bb.y, bb.z, bb.w};
#pragma unroll
      for (int i = 0; i < 8; ++i) acc[i] = fmaxf(fmaf(acc[i], di, bias[i]), 0.f);
    } else {
      if (q == 0) sdinv[nl] = 0.f;
#pragma unroll
      for (int i = 0; i < 8; ++i) acc[i] = 0.f;
    }
    *(uint4*)&As[nl * LDA + q * 8] = pack8(acc);
  }
  __syncthreads();

  {
    const int wave = tid >> 6;
    const int lane = tid & 63;
    const int q = lane >> 4;
    const int l15 = lane & 15;
    f32x4 acc = {0.0f, 0.0f, 0.0f, 0.0f};
#pragma unroll
    for (int kk = 0; kk < 4; ++kk) {
      ABu a, b;
      a.u4 = *(const uint4*)&As[l15 * LDA + kk * 32 + q * 8];
      b.u4 = *(const uint4*)(Wb2 + ((size_t)(kk * 4 + q) * 64 + wave * 16 + l15) * 8);
      acc = __builtin_amdgcn_mfma_f32_16x16x32_bf16(a.v, b.v, acc, 0, 0, 0);
    }
#pragma unroll
    for (int v = 0; v < 4; ++v) {
      int rl = q * 4 + v;
      int row = blockIdx.x * 16 + rl;
      if (row < n) h2s[(size_t)row * 64 + wave * 16 + l15] = f2bf(acc[v] * sdinv[rl]);
    }
  }
}

// ---------------- 8: agg2 ----------------
__global__ __launch_bounds__(256) void k_agg2(const unsigned short* __restrict__ h2s,
                                              const float* __restrict__ dinv,
                                              const float* __restrict__ b2,
                                              const int* __restrict__ offsets,
                                              const int* __restrict__ esrc,
                                              float* __restrict__ out, int n) {
  constexpr int CQ = 8;  // 64 ch / 8 per lane
  const int tid = threadIdx.x;
  const int node = blockIdx.x * 32 + tid / CQ;
  const int q = tid % CQ;
  if (node >= n) return;

  const uint4* h4 = (const uint4*)h2s;
  float di = dinv[node];
  float acc[8];
  unpack8(h4[(size_t)node * CQ + q], acc);

  int e0 = offsets[node];
  int e1 = offsets[node + 1];
  for (int e = e0; e < e1; e += 8) {
    int idx[8];
#pragma unroll
    for (int i = 0; i < 8; ++i) {
      int ee = e + i < e1 ? e + i : e1 - 1;
      idx[i] = esrc[ee];
    }
    uint4 rr[8];
#pragma unroll
    for (int i = 0; i < 8; ++i) rr[i] = h4[(size_t)idx[i] * CQ + q];
#pragma unroll
    for (int i = 0; i < 8; ++i) {
      float w = (e + i < e1) ? 1.f : 0.f;
      float g[8];
      unpack8(rr[i], g);
#pragma unroll
      for (int j = 0; j < 8; ++j) acc[j] = fmaf(g[j], w, acc[j]);
    }
  }

  const float4* b24 = (const float4*)b2;
  float4 ba = b24[q * 2], bb = b24[q * 2 + 1];
  float bias[8] = {ba.x, ba.y, ba.z, ba.w, bb.x, bb.y, bb.z, bb.w};
  float4 o0, o1;
  o0.x = fmaf(acc[0], di, bias[0]);
  o0.y = fmaf(acc[1], di, bias[1]);
  o0.z = fmaf(acc[2], di, bias[2]);
  o0.w = fmaf(acc[3], di, bias[3]);
  o1.x = fmaf(acc[4], di, bias[4]);
  o1.y = fmaf(acc[5], di, bias[5]);
  o1.z = fmaf(acc[6], di, bias[6]);
  o1.w = fmaf(acc[7], di, bias[7]);
  ((float4*)out)[(size_t)node * 16 + q * 2 + 0] = o0;
  ((float4*)out)[(size_t)node * 16 + q * 2 + 1] = o1;
}

// ---------------- launch ----------------

extern "C" void kernel_launch(void* const* d_in, const int* in_sizes, int n_in,
                              void* d_out, int out_size, void* d_ws, size_t ws_size,
                              hipStream_t stream) {
  const float* x  = (const float*)d_in[0];
  const float* W1 = (const float*)d_in[1];
  const float* b1 = (const float*)d_in[2];
  const float* W2 = (const float*)d_in[3];
  const float* b2 = (const float*)d_in[4];
  const int* src  = (const int*)d_in[5];
  const int* dst  = (const int*)d_in[6];
  float* out = (float*)d_out;

  constexpr int IN_C = 128, HID_C = 128, OUT_C = 64;
  const int N = in_sizes[0] / IN_C;   // 100000
  const int E = in_sizes[5];          // 600000

  char* p = (char*)d_ws;
  auto alloc = [&](size_t bytes) {
    char* r = p;
    p += (bytes + 255) & ~(size_t)255;
    return r;
  };
  float* dinv    = (float*)alloc((size_t)N * 4);
  int*   offsets = (int*)alloc((size_t)(N + 1) * 4);
  int*   counts  = (int*)alloc((size_t)NG * N * 4);
  int*   gbase   = (int*)alloc((size_t)NG * N * 4);
  int*   rank    = (int*)alloc((size_t)E * 4);
  int*   aux     = (int*)alloc(1024);
  int*   esrc    = (int*)alloc((size_t)E * 4);
  unsigned short* Wb1 = (unsigned short*)alloc((size_t)IN_C * HID_C * 2);
  unsigned short* Wb2 = (unsigned short*)alloc((size_t)HID_C * OUT_C * 2);
  unsigned short* h1s = (unsigned short*)alloc((size_t)N * HID_C * 2);
  unsigned short* h2s = (unsigned short*)alloc((size_t)N * OUT_C * 2);

  const int T = 256;
  const int G = (N + SCAN_CHUNK - 1) / SCAN_CHUNK;  // 98 (<= 256)
  const int E4B = ((E + 3) / 4 + T - 1) / T;        // 4-edge/thread blocks
  constexpr int CONV_BLOCKS = (128 * 128 + 128 * 64) / 256;

  k_pre<<<CONV_BLOCKS + (NG * N + T - 1) / T, T, 0, stream>>>(W1, W2, Wb1, Wb2,
                                                              counts, NG * N);
  k_count_rank<<<E4B, T, 0, stream>>>(dst, counts, rank, E, N);
  k_scan1<<<G, T, 0, stream>>>(counts, offsets, gbase, aux, dinv, N);
  k_scan3<<<(N + T - 1) / T, T, 0, stream>>>(offsets, gbase, aux, N, E, G);
  k_scatter<<<E4B, T, 0, stream>>>(src, dst, gbase, rank, esrc, E, N);
  k_gemm1<<<(N + 63) / 64, T, 0, stream>>>(x, Wb1, dinv, h1s, N);
  k_aggemm<<<(N + 15) / 16, T, 0, stream>>>(h1s, dinv, b1, offsets, esrc, Wb2, h2s, N);
  k_agg2<<<(N + 31) / 32, T, 0, stream>>>(h2s, dinv, b2, offsets, esrc, out, N);
}